// Round 18
// baseline (147.856 us; speedup 1.0000x reference)
//
#include <hip/hip_runtime.h>

typedef unsigned short u16;
typedef __attribute__((ext_vector_type(8))) short bf16x8;
typedef __attribute__((ext_vector_type(4))) short u16x4;
typedef __attribute__((ext_vector_type(4))) float f32x4;

__device__ __forceinline__ u16 f2bu(float f) {
  union { float f; unsigned u; } v; v.f = f;
  unsigned r = v.u + 0x7fffu + ((v.u >> 16) & 1u);
  return (u16)(r >> 16);
}
__device__ __forceinline__ u16 f2bu_fast(float f) {   // round-half-up, 2 ops
  union { float f; unsigned u; } v; v.f = f;
  return (u16)((v.u + 0x8000u) >> 16);
}
__device__ __forceinline__ float b2f(u16 s) {
  union { unsigned u; float f; } v; v.u = ((unsigned)s) << 16;
  return v.f;
}
__device__ __forceinline__ bf16x8 cvt8(float4 a, float4 b) {
  bf16x8 r;
  r[0] = (short)f2bu(a.x); r[1] = (short)f2bu(a.y);
  r[2] = (short)f2bu(a.z); r[3] = (short)f2bu(a.w);
  r[4] = (short)f2bu(b.x); r[5] = (short)f2bu(b.y);
  r[6] = (short)f2bu(b.z); r[7] = (short)f2bu(b.w);
  return r;
}
__device__ __forceinline__ f32x4 mfma16(bf16x8 a, bf16x8 b, f32x4 c) {
  return __builtin_amdgcn_mfma_f32_16x16x32_bf16(a, b, c, 0, 0, 0);
}

// ---------------- merged prep: ballot-mask (0..16383) + cvt (16384..20479) + table (20480..20519)
__global__ __launch_bounds__(256) void prep_all_k(
    const int* __restrict__ mask, unsigned long long* __restrict__ bm64,
    const float* __restrict__ x, const float* __restrict__ w,
    const float* __restrict__ o, u16* __restrict__ xb,
    u16* __restrict__ wbo, u16* __restrict__ ob,
    const float* __restrict__ tbl, u16* __restrict__ tb, u16* __restrict__ tbT) {
  int bid = blockIdx.x;
  if (bid < 16384) {              // mask -> 64-bit words, fully coalesced
    int i = bid * 256 + threadIdx.x;
    unsigned long long bits = __ballot(mask[i] != 0);
    if ((threadIdx.x & 63) == 0) bm64[i >> 6] = bits;
  } else if (bid < 20480) {       // fp32 -> bf16 bulk converts
    int cb = bid - 16384;
    const float* src; u16* dst; int off;
    if (cb < 2048)      { src = x; dst = xb;  off = cb * 2048; }
    else if (cb < 3584) { src = w; dst = wbo; off = (cb - 2048) * 2048; }
    else                { src = o; dst = ob;  off = (cb - 3584) * 2048; }
    int idx = off + threadIdx.x * 8;
    float4 a = *(const float4*)(src + idx);
    float4 b = *(const float4*)(src + idx + 4);
    *(bf16x8*)(dst + idx) = cvt8(a, b);
  } else {                        // table: [160][64] (pad zero) + transpose [64][160]
    int idx = (bid - 20480) * 256 + threadIdx.x;
    int r = idx >> 6, d = idx & 63;
    float v = (r < 129) ? tbl[r * 64 + d] : 0.f;
    u16 bv = f2bu(v);
    tb[r * 64 + d] = bv;
    tbT[d * 160 + r] = bv;
  }
}

// ---------------- QKV GEMM (bf16 in, dbuf LDS, depth-2 prefetch, 1 barrier/K-step)
__global__ __launch_bounds__(256) void gemm_qkv_k(
    const u16* __restrict__ A, const u16* __restrict__ Bw,
    const float* __restrict__ bias,
    u16* __restrict__ qb, u16* __restrict__ kb, u16* __restrict__ vt) {
  __shared__ u16 As[2][128][40];
  __shared__ u16 Bs[2][128][40];
  const int tid = threadIdx.x;
  const int l = tid & 63, w = tid >> 6;
  const int wr = w >> 1, wc = w & 1;
  const int fr = l & 15, kq = (l >> 4) * 8;
  const int bid = blockIdx.x;
  const int tn = (bid % 24) * 128, tm = (bid / 24) * 128;
  const int sr = tid >> 1, sc = (tid & 1) * 16;
  const u16* Ag = A + (size_t)(tm + sr) * 1024 + sc;
  const u16* Bg = Bw + (size_t)(tn + sr) * 1024 + sc;
  f32x4 acc[4][4] = {};
  auto compute = [&](int db) {
    bf16x8 af[4], bfv[4];
#pragma unroll
    for (int mi = 0; mi < 4; ++mi) af[mi] = *(const bf16x8*)&As[db][wr * 64 + mi * 16 + fr][kq];
#pragma unroll
    for (int ni = 0; ni < 4; ++ni) bfv[ni] = *(const bf16x8*)&Bs[db][wc * 64 + ni * 16 + fr][kq];
#pragma unroll
    for (int mi = 0; mi < 4; ++mi)
#pragma unroll
      for (int ni = 0; ni < 4; ++ni)
        acc[mi][ni] = mfma16(af[mi], bfv[ni], acc[mi][ni]);
  };
  bf16x8 aX0, aX1, bX0, bX1, aY0, aY1, bY0, bY1;
  aX0 = *(const bf16x8*)(Ag);        aX1 = *(const bf16x8*)(Ag + 8);
  bX0 = *(const bf16x8*)(Bg);        bX1 = *(const bf16x8*)(Bg + 8);
  aY0 = *(const bf16x8*)(Ag + 32);   aY1 = *(const bf16x8*)(Ag + 40);
  bY0 = *(const bf16x8*)(Bg + 32);   bY1 = *(const bf16x8*)(Bg + 40);
#pragma unroll 1
  for (int kt = 0; kt < 32; kt += 2) {
    *(bf16x8*)&As[0][sr][sc] = aX0; *(bf16x8*)&As[0][sr][sc + 8] = aX1;
    *(bf16x8*)&Bs[0][sr][sc] = bX0; *(bf16x8*)&Bs[0][sr][sc + 8] = bX1;
    __syncthreads();
    if (kt + 2 < 32) {
      aX0 = *(const bf16x8*)(Ag + (kt + 2) * 32);
      aX1 = *(const bf16x8*)(Ag + (kt + 2) * 32 + 8);
      bX0 = *(const bf16x8*)(Bg + (kt + 2) * 32);
      bX1 = *(const bf16x8*)(Bg + (kt + 2) * 32 + 8);
    }
    compute(0);
    *(bf16x8*)&As[1][sr][sc] = aY0; *(bf16x8*)&As[1][sr][sc + 8] = aY1;
    *(bf16x8*)&Bs[1][sr][sc] = bY0; *(bf16x8*)&Bs[1][sr][sc + 8] = bY1;
    __syncthreads();
    if (kt + 3 < 32) {
      aY0 = *(const bf16x8*)(Ag + (kt + 3) * 32);
      aY1 = *(const bf16x8*)(Ag + (kt + 3) * 32 + 8);
      bY0 = *(const bf16x8*)(Bg + (kt + 3) * 32);
      bY1 = *(const bf16x8*)(Bg + (kt + 3) * 32 + 8);
    }
    compute(1);
  }
#pragma unroll
  for (int mi = 0; mi < 4; ++mi)
#pragma unroll
    for (int ni = 0; ni < 4; ++ni)
#pragma unroll
      for (int j = 0; j < 4; ++j) {
        int gm = tm + wr * 64 + mi * 16 + (l >> 4) * 4 + j;
        int gn = tn + wc * 64 + ni * 16 + fr;
        float v = acc[mi][ni][j] + bias[gn];
        int b = gm >> 10, s = gm & 1023;
        unsigned gnu = (unsigned)gn;
        unsigned h = gnu / 192u;
        unsigned rem = gnu - h * 192u;
        unsigned which = rem >> 6, d = rem & 63u;
        int bh = b * 16 + (int)h;
        u16 bv = f2bu(v);
        if (which == 0u)      qb[((size_t)bh * 1024 + s) * 64 + d] = bv;
        else if (which == 1u) kb[((size_t)bh * 1024 + s) * 64 + d] = bv;
        else                  vt[((size_t)bh * 64 + d) * 1024 + s] = bv;
      }
}

// ---------------- attention: swapped-QK register-P; block = (bh, 64 q-rows), 4 waves
// K/V LDS-staged+shared; merged qrel/band buffer (in-place overwrite) -> 4 blocks/CU
#define QRS 132    // merged qrel/band row stride u16 (264B -> conflict-free b128 reads)
__global__ __launch_bounds__(256) void attn_k(
    const u16* __restrict__ qb, const u16* __restrict__ kb,
    const u16* __restrict__ vt, const u16* __restrict__ tb,
    const u16* __restrict__ tbT, const unsigned long long* __restrict__ bm64,
    u16* __restrict__ vals) {
  __shared__ u16 Kbuf[64 * 64];        // 8 KB: K chunk [64 k][64 d], slot^=(k&7)
  __shared__ u16 Vbuf[64 * 64];        // 8 KB: V^T chunk [64 d][64 k-permuted], slot^=(d&7)
  __shared__ u16 qrs[64 * QRS];        // 16.9 KB: qrel[q][r] -> overwritten by band P in place
  const int tid = threadIdx.x;
  const int l = tid & 63, w = tid >> 6;
  const int fr = l & 15, g = l >> 4, kq = g * 8, g4 = g * 4;
  const int blk = ((int)blockIdx.x & 7) * 128 + ((int)blockIdx.x >> 3);  // XCD swizzle
  const int qt = blk & 15, bh = blk >> 4;
  const int b = bh >> 4, h = bh & 15;
  const int qbase = qt * 64 + w * 16;            // this wave's q-row base
  const int q = qbase + fr;                      // this LANE's q-row (swapped layout)
  const u16* kbase = kb + (size_t)bh * 65536;
  const u16* vbase = vt + (size_t)bh * 65536;
  // staging regs + loaders (cooperative across all 256 threads)
  const int srow0 = tid >> 3, sslot = tid & 7;
  const int p5 = (sslot >> 2) & 1, p4 = (sslot >> 1) & 1, p3 = sslot & 1;
  const int vb0 = p5 * 32 + p3 * 16 + p4 * 4;    // V permuted-store base (u16 units)
  bf16x8 sK0, sK1, sV0, sV1;
  auto ldStage = [&](int c) {
    const u16* ks = kbase + (size_t)(c * 64) * 64;
    sK0 = *(const bf16x8*)(ks + srow0 * 64 + sslot * 8);
    sK1 = *(const bf16x8*)(ks + (srow0 + 32) * 64 + sslot * 8);
    const u16* vs = vbase + c * 64 + sslot * 8;
    sV0 = *(const bf16x8*)(vs + (size_t)srow0 * 1024);
    sV1 = *(const bf16x8*)(vs + (size_t)(srow0 + 32) * 1024);
  };
  auto wrV = [&](int d, bf16x8 v) {
    int s0 = vb0 >> 3, sub = vb0 & 7;
    int a0 = d * 64 + ((s0 ^ (d & 7)) * 8 + sub);
    int a1 = d * 64 + (((s0 + 1) ^ (d & 7)) * 8 + sub);
    u16x4 lo = {v[0], v[1], v[2], v[3]};
    u16x4 hi = {v[4], v[5], v[6], v[7]};
    *(u16x4*)&Vbuf[a0] = lo;
    *(u16x4*)&Vbuf[a1] = hi;
  };
  auto wrStage = [&]() {
    *(bf16x8*)&Kbuf[srow0 * 64 + (sslot ^ (srow0 & 7)) * 8] = sK0;
    *(bf16x8*)&Kbuf[(srow0 + 32) * 64 + (sslot ^ ((srow0 + 32) & 7)) * 8] = sK1;
    wrV(srow0, sV0);
    wrV(srow0 + 32, sV1);
  };
  ldStage(0);                                    // issue chunk-0 loads early
  // Q fragments (lane fr holds q-row qbase+fr)
  const u16* qrow = qb + ((size_t)bh * 1024 + qbase) * 64;
  bf16x8 qa0 = *(const bf16x8*)(qrow + fr * 64 + kq);
  bf16x8 qa1 = *(const bf16x8*)(qrow + fr * 64 + 32 + kq);
  // pass 0 (swapped): qrel[q=fr][r = t*16+g4+j]
  f32x4 a_t0 = {}, a_t8 = {};
#pragma unroll
  for (int t = 0; t < 9; ++t) {
    const u16* tp = tb + (t * 16 + fr) * 64 + kq;
    bf16x8 t0 = *(const bf16x8*)(tp);
    bf16x8 t1 = *(const bf16x8*)(tp + 32);
    f32x4 a = {0.f, 0.f, 0.f, 0.f};
    a = mfma16(t0, qa0, a);
    a = mfma16(t1, qa1, a);
#pragma unroll
    for (int j = 0; j < 4; ++j) {
      int rg = t * 16 + g4 + j;
      if (rg < 129) qrs[(w * 16 + fr) * QRS + rg] = f2bu(a[j]);
    }
    if (t == 0) a_t0 = a;
    if (t == 8) a_t8 = a;
  }
  const float q0r = __shfl(a_t0[0], fr);     // qrel[q=fr][0]
  const float q128r = __shfl(a_t8[0], fr);   // qrel[q=fr][128]
  u16* qpl = qrs + (w * 16 + fr) * QRS;      // this lane's merged qrel/band row
  // targeted zeroing: band slots whose k is out-of-range or clip_pad-edge are never
  // written by pass-1 (and their qrel value is never read) -> must read as 0 in band MFMA
  if (g == 0) {
    int loEnd = (q == 0) ? 63 : (q <= 63 ? 64 - q : 0);
    for (int r = 1; r <= loEnd; ++r) qpl[r] = 0;
    int hiStart = (q >= 960 && q <= 1022) ? (1087 - q) : (q == 1023 ? 65 : 128);
    for (int r = hiStart; r <= 127; ++r) qpl[r] = 0;
  }
  // mask: one u64 per (q, chunk); prefetch next chunk's words
  const unsigned* bmp = (const unsigned*)(bm64 + (((size_t)b << 10) + q) * 16);
  unsigned bmLoX = bmp[0], bmHiX = bmp[1], bmLoY = 0, bmHiY = 0;
  const float C1 = 0.18033688011112042f;   // 0.125*log2(e)
  const float C2 = 17.31234049066756f;     // 12*log2(e)
  float ps = 0.f, psA = 0.f, psB = 0.f;
  f32x4 acc[4] = {};
  auto kfrag = [&](int t2, int hh) -> bf16x8 {
    int rk = t2 * 16 + fr;
    int sl = (g + 4 * hh) ^ (rk & 7);
    return *(const bf16x8*)&Kbuf[rk * 64 + sl * 8];
  };
  auto vfrag = [&](int dg, int hh) -> bf16x8 {
    int d = dg * 16 + fr;
    int sl = (hh * 4 + g) ^ (d & 7);
    return *(const bf16x8*)&Vbuf[d * 64 + sl * 8];
  };
#pragma unroll 1
  for (int c = 0; c < 16; ++c) {
    __syncthreads();                     // all waves done reading prev chunk bufs
    wrStage();                           // write staged chunk c (waits its vmcnt)
    __syncthreads();                     // bufs ready
    __builtin_amdgcn_s_setprio(1);
    if (c < 15) {
      ldStage(c + 1);                    // next chunk global loads (hidden by compute)
      bmLoY = bmp[(c + 1) * 2];
      bmHiY = bmp[(c + 1) * 2 + 1];
    }
    bf16x8 pa0, pa1;                     // P fragments (built in registers)
#pragma unroll
    for (int t2 = 0; t2 < 4; ++t2) {
      f32x4 a = {0.f, 0.f, 0.f, 0.f};
      a = mfma16(kfrag(t2, 0), qa0, a);  // swapped: lane holds S[k=g4+j][q=fr]
      a = mfma16(kfrag(t2, 1), qa1, a);
      int ncol = c * 64 + t2 * 16;
      unsigned wsel = (t2 < 2) ? bmLoX : bmHiX;
      if (ncol + 79 <= qbase) {          // whole tile: rdx = 0
#pragma unroll
        for (int j = 0; j < 4; ++j) {
          float s = a[j] + q0r;
          unsigned bit = (wsel >> (g4 + ((t2 & 1) * 16 + j))) & 1u;
          float arg = bit ? __builtin_fmaf(s, C1, -C2) : -1e30f;
          float e = __builtin_amdgcn_exp2f(arg);
          ps += e; psA += e;
          u16 pv = f2bu_fast(e);
          if (t2 < 2) pa0[t2 * 4 + j] = (short)pv; else pa1[(t2 - 2) * 4 + j] = (short)pv;
        }
      } else if (ncol >= qbase + 79) {   // whole tile: rdx = 128
#pragma unroll
        for (int j = 0; j < 4; ++j) {
          float s = a[j] + q128r;
          unsigned bit = (wsel >> (g4 + ((t2 & 1) * 16 + j))) & 1u;
          float arg = bit ? __builtin_fmaf(s, C1, -C2) : -1e30f;
          float e = __builtin_amdgcn_exp2f(arg);
          ps += e; psB += e;
          u16 pv = f2bu_fast(e);
          if (t2 < 2) pa0[t2 * 4 + j] = (short)pv; else pa1[(t2 - 2) * 4 + j] = (short)pv;
        }
      } else {                            // mixed tile: read qrel slot, overwrite with P
#pragma unroll
        for (int j = 0; j < 4; ++j) {
          int kgl = ncol + g4 + j;
          int dd = kgl - q;
          int rdx = dd < -64 ? 0 : (dd > 64 ? 128 : dd + 64);
          bool ov = (q >= 1 && q <= 1022);
          bool edge = ov && (kgl == 0 || kgl == 1023);
          if (edge) rdx = (kgl == 0) ? 0 : 128;
          float s = a[j] + b2f(qpl[rdx]);
          unsigned bit = (wsel >> (g4 + ((t2 & 1) * 16 + j))) & 1u;
          float arg = bit ? __builtin_fmaf(s, C1, -C2) : -1e30f;
          float e = __builtin_amdgcn_exp2f(arg);
          ps += e;
          psA += (rdx == 0) ? e : 0.f;
          psB += (rdx == 128) ? e : 0.f;
          u16 pv = f2bu_fast(e);
          if (t2 < 2) pa0[t2 * 4 + j] = (short)pv; else pa1[(t2 - 2) * 4 + j] = (short)pv;
          int r = dd + 64;
          if (r >= 1 && r <= 127 && !edge) qpl[r] = pv;   // in-place band store
        }
      }
    }
    // PV: P-in-registers (k-permuted) x V (stored in matching k-order)
#pragma unroll
    for (int dg = 0; dg < 4; ++dg) {
      acc[dg] = mfma16(pa0, vfrag(dg, 0), acc[dg]);
      acc[dg] = mfma16(pa1, vfrag(dg, 1), acc[dg]);
    }
    __builtin_amdgcn_s_setprio(0);
    bmLoX = bmLoY; bmHiX = bmHiY;
  }
  // slot 0 held qrel[0] for pass-1; band MFMA needs 0 there (r=0 via rank-1 term)
  if (g == 0) qpl[0] = 0;
  // reduce row sums across the 4 groups (each lane then holds totals for q=fr)
#pragma unroll
  for (int off = 16; off <= 32; off <<= 1) {
    ps += __shfl_xor(ps, off);
    psA += __shfl_xor(psA, off);
    psB += __shfl_xor(psB, off);
  }
  // redistribute to output layout (elem j -> q-row g4+j)
  float psO[4], psAO[4], psBO[4];
#pragma unroll
  for (int j = 0; j < 4; ++j) {
    psO[j] = __shfl(ps, g4 + j);
    psAO[j] = __shfl(psA, g4 + j);
    psBO[j] = __shfl(psB, g4 + j);
  }
  // band MFMAs + rank-1 r=0/128 + normalize + store
  const u16* srow = qrs + (w * 16 + fr) * QRS + kq;
  bf16x8 sa0 = *(const bf16x8*)(srow);
  bf16x8 sa1 = *(const bf16x8*)(srow + 32);
  bf16x8 sa2 = *(const bf16x8*)(srow + 64);
  bf16x8 sa3 = *(const bf16x8*)(srow + 96);
#pragma unroll
  for (int dg = 0; dg < 4; ++dg) {
    int dc = dg * 16 + fr;
    const u16* tq = tbT + dc * 160 + kq;
    f32x4 av = acc[dg];
    av = mfma16(sa0, *(const bf16x8*)(tq), av);
    av = mfma16(sa1, *(const bf16x8*)(tq + 32), av);
    av = mfma16(sa2, *(const bf16x8*)(tq + 64), av);
    av = mfma16(sa3, *(const bf16x8*)(tq + 96), av);
    float t0v = b2f(tb[dc]);
    float t128v = b2f(tb[128 * 64 + dc]);
#pragma unroll
    for (int j = 0; j < 4; ++j) {
      float val = (av[j] + psAO[j] * t0v + psBO[j] * t128v) / psO[j];
      int sg = qbase + g4 + j;
      vals[((size_t)b * 1024 + sg) * 1024 + h * 64 + dc] = f2bu(val);
    }
  }
}

// ---------------- output GEMM (bf16 in, dbuf LDS, depth-2 prefetch)
__global__ __launch_bounds__(256) void gemm_out_k(
    const u16* __restrict__ A, const u16* __restrict__ Bw,
    const float* __restrict__ bias, float* __restrict__ out) {
  __shared__ u16 As[2][128][40];
  __shared__ u16 Bs[2][128][40];
  const int tid = threadIdx.x;
  const int l = tid & 63, w = tid >> 6;
  const int wr = w >> 1, wc = w & 1;
  const int fr = l & 15, kq = (l >> 4) * 8;
  const int bid = blockIdx.x;
  const int tn = (bid % 8) * 128, tm = (bid / 8) * 128;
  const int sr = tid >> 1, sc = (tid & 1) * 16;
  const u16* Ag = A + (size_t)(tm + sr) * 1024 + sc;
  const u16* Bg = Bw + (size_t)(tn + sr) * 1024 + sc;
  f32x4 acc[4][4] = {};
  auto compute = [&](int db) {
    bf16x8 af[4], bfv[4];
#pragma unroll
    for (int mi = 0; mi < 4; ++mi) af[mi] = *(const bf16x8*)&As[db][wr * 64 + mi * 16 + fr][kq];
#pragma unroll
    for (int ni = 0; ni < 4; ++ni) bfv[ni] = *(const bf16x8*)&Bs[db][wc * 64 + ni * 16 + fr][kq];
#pragma unroll
    for (int mi = 0; mi < 4; ++mi)
#pragma unroll
      for (int ni = 0; ni < 4; ++ni)
        acc[mi][ni] = mfma16(af[mi], bfv[ni], acc[mi][ni]);
  };
  bf16x8 aX0, aX1, bX0, bX1, aY0, aY1, bY0, bY1;
  aX0 = *(const bf16x8*)(Ag);        aX1 = *(const bf16x8*)(Ag + 8);
  bX0 = *(const bf16x8*)(Bg);        bX1 = *(const bf16x8*)(Bg + 8);
  aY0 = *(const bf16x8*)(Ag + 32);   aY1 = *(const bf16x8*)(Ag + 40);
  bY0 = *(const bf16x8*)(Bg + 32);   bY1 = *(const bf16x8*)(Bg + 40);
#pragma unroll 1
  for (int kt = 0; kt < 32; kt += 2) {
    *(bf16x8*)&As[0][sr][sc] = aX0; *(bf16x8*)&As[0][sr][sc + 8] = aX1;
    *(bf16x8*)&Bs[0][sr][sc] = bX0; *(bf16x8*)&Bs[0][sr][sc + 8] = bX1;
    __syncthreads();
    if (kt + 2 < 32) {
      aX0 = *(const bf16x8*)(Ag + (kt + 2) * 32);
      aX1 = *(const bf16x8*)(Ag + (kt + 2) * 32 + 8);
      bX0 = *(const bf16x8*)(Bg + (kt + 2) * 32);
      bX1 = *(const bf16x8*)(Bg + (kt + 2) * 32 + 8);
    }
    compute(0);
    *(bf16x8*)&As[1][sr][sc] = aY0; *(bf16x8*)&As[1][sr][sc + 8] = aY1;
    *(bf16x8*)&Bs[1][sr][sc] = bY0; *(bf16x8*)&Bs[1][sr][sc + 8] = bY1;
    __syncthreads();
    if (kt + 3 < 32) {
      aY0 = *(const bf16x8*)(Ag + (kt + 3) * 32);
      aY1 = *(const bf16x8*)(Ag + (kt + 3) * 32 + 8);
      bY0 = *(const bf16x8*)(Bg + (kt + 3) * 32);
      bY1 = *(const bf16x8*)(Bg + (kt + 3) * 32 + 8);
    }
    compute(1);
  }
#pragma unroll
  for (int mi = 0; mi < 4; ++mi)
#pragma unroll
    for (int ni = 0; ni < 4; ++ni)
#pragma unroll
      for (int j = 0; j < 4; ++j) {
        int gm = tm + wr * 64 + mi * 16 + (l >> 4) * 4 + j;
        int gn = tn + wc * 64 + ni * 16 + fr;
        out[(size_t)gm * 1024 + gn] = acc[mi][ni][j] + bias[gn];
      }
}

extern "C" void kernel_launch(void* const* d_in, const int* in_sizes, int n_in,
                              void* d_out, int out_size, void* d_ws, size_t ws_size,
                              hipStream_t stream) {
  (void)in_sizes; (void)n_in; (void)out_size; (void)ws_size;
  const float* x    = (const float*)d_in[0];
  const float* qkvw = (const float*)d_in[1];
  const float* qkvb = (const float*)d_in[2];
  const float* ow   = (const float*)d_in[3];
  const float* ob   = (const float*)d_in[4];
  const float* tbl  = (const float*)d_in[5];
  const int*   mask = (const int*)d_in[6];
  float* out = (float*)d_out;
  char* ws = (char*)d_ws;
  u16* tb   = (u16*)(ws);
  u16* tbT  = (u16*)(ws + 20480);
  u16* qb   = (u16*)(ws + 40960);
  u16* kb   = (u16*)(ws + 40960 + 8388608ull);
  u16* vt   = (u16*)(ws + 40960 + 2ull * 8388608ull);
  u16* xbvals = (u16*)(ws + 40960 + 3ull * 8388608ull);   // xb (pre-attn) / vals (post)
  unsigned long long* bm64 = (unsigned long long*)(ws + 40960 + 4ull * 8388608ull);
  u16* wb   = (u16*)(ws + 40960 + 4ull * 8388608ull + 524288ull);
  u16* owb  = (u16*)(ws + 40960 + 4ull * 8388608ull + 524288ull + 6291456ull);

  prep_all_k<<<dim3(20520), dim3(256), 0, stream>>>(mask, bm64, x, qkvw, ow,
                                                    xbvals, wb, owb, tbl, tb, tbT);
  gemm_qkv_k<<<dim3(768), dim3(256), 0, stream>>>(xbvals, wb, qkvb, qb, kb, vt);
  attn_k<<<dim3(1024), dim3(256), 0, stream>>>(qb, kb, vt, tb, tbT, bm64, xbvals);
  gemm_out_k<<<dim3(256), dim3(256), 0, stream>>>(xbvals, owb, ob, out);
}

// Round 19
// 132.160 us; speedup vs baseline: 1.1188x; 1.1188x over previous
//
#include <hip/hip_runtime.h>

typedef unsigned short u16;
typedef __attribute__((ext_vector_type(8))) short bf16x8;
typedef __attribute__((ext_vector_type(4))) short u16x4;
typedef __attribute__((ext_vector_type(4))) float f32x4;

__device__ __forceinline__ u16 f2bu(float f) {
  union { float f; unsigned u; } v; v.f = f;
  unsigned r = v.u + 0x7fffu + ((v.u >> 16) & 1u);
  return (u16)(r >> 16);
}
__device__ __forceinline__ u16 f2bu_fast(float f) {   // round-half-up, 2 ops
  union { float f; unsigned u; } v; v.f = f;
  return (u16)((v.u + 0x8000u) >> 16);
}
__device__ __forceinline__ float b2f(u16 s) {
  union { unsigned u; float f; } v; v.u = ((unsigned)s) << 16;
  return v.f;
}
__device__ __forceinline__ bf16x8 cvt8(float4 a, float4 b) {
  bf16x8 r;
  r[0] = (short)f2bu(a.x); r[1] = (short)f2bu(a.y);
  r[2] = (short)f2bu(a.z); r[3] = (short)f2bu(a.w);
  r[4] = (short)f2bu(b.x); r[5] = (short)f2bu(b.y);
  r[6] = (short)f2bu(b.z); r[7] = (short)f2bu(b.w);
  return r;
}
__device__ __forceinline__ f32x4 mfma16(bf16x8 a, bf16x8 b, f32x4 c) {
  return __builtin_amdgcn_mfma_f32_16x16x32_bf16(a, b, c, 0, 0, 0);
}

// ---------------- merged prep: ballot-mask (0..16383) + cvt (16384..20479) + table (20480..20519)
__global__ __launch_bounds__(256) void prep_all_k(
    const int* __restrict__ mask, unsigned long long* __restrict__ bm64,
    const float* __restrict__ x, const float* __restrict__ w,
    const float* __restrict__ o, u16* __restrict__ xb,
    u16* __restrict__ wbo, u16* __restrict__ ob,
    const float* __restrict__ tbl, u16* __restrict__ tb, u16* __restrict__ tbT) {
  int bid = blockIdx.x;
  if (bid < 16384) {              // mask -> 64-bit words, fully coalesced
    int i = bid * 256 + threadIdx.x;
    unsigned long long bits = __ballot(mask[i] != 0);
    if ((threadIdx.x & 63) == 0) bm64[i >> 6] = bits;
  } else if (bid < 20480) {       // fp32 -> bf16 bulk converts
    int cb = bid - 16384;
    const float* src; u16* dst; int off;
    if (cb < 2048)      { src = x; dst = xb;  off = cb * 2048; }
    else if (cb < 3584) { src = w; dst = wbo; off = (cb - 2048) * 2048; }
    else                { src = o; dst = ob;  off = (cb - 3584) * 2048; }
    int idx = off + threadIdx.x * 8;
    float4 a = *(const float4*)(src + idx);
    float4 b = *(const float4*)(src + idx + 4);
    *(bf16x8*)(dst + idx) = cvt8(a, b);
  } else {                        // table: [160][64] (pad zero) + transpose [64][160]
    int idx = (bid - 20480) * 256 + threadIdx.x;
    int r = idx >> 6, d = idx & 63;
    float v = (r < 129) ? tbl[r * 64 + d] : 0.f;
    u16 bv = f2bu(v);
    tb[r * 64 + d] = bv;
    tbT[d * 160 + r] = bv;
  }
}

// ---------------- QKV GEMM (bf16 in, dbuf LDS, 1 barrier/K-step, loads pre-barrier)
__global__ __launch_bounds__(256) void gemm_qkv_k(
    const u16* __restrict__ A, const u16* __restrict__ Bw,
    const float* __restrict__ bias,
    u16* __restrict__ qb, u16* __restrict__ kb, u16* __restrict__ vt) {
  __shared__ u16 As[2][128][40];
  __shared__ u16 Bs[2][128][40];
  const int tid = threadIdx.x;
  const int l = tid & 63, w = tid >> 6;
  const int wr = w >> 1, wc = w & 1;
  const int fr = l & 15, kq = (l >> 4) * 8;
  const int bid = blockIdx.x;
  const int tn = (bid % 24) * 128, tm = (bid / 24) * 128;
  const int sr = tid >> 1, sc = (tid & 1) * 16;
  const u16* Ag = A + (size_t)(tm + sr) * 1024 + sc;
  const u16* Bg = Bw + (size_t)(tn + sr) * 1024 + sc;
  f32x4 acc[4][4] = {};
  bf16x8 a0, a1, b0, b1;
  a0 = *(const bf16x8*)(Ag);      a1 = *(const bf16x8*)(Ag + 8);
  b0 = *(const bf16x8*)(Bg);      b1 = *(const bf16x8*)(Bg + 8);
#pragma unroll 1
  for (int kt = 0; kt < 32; ++kt) {
    const int db = kt & 1;
    *(bf16x8*)&As[db][sr][sc] = a0; *(bf16x8*)&As[db][sr][sc + 8] = a1;
    *(bf16x8*)&Bs[db][sr][sc] = b0; *(bf16x8*)&Bs[db][sr][sc + 8] = b1;
    if (kt < 31) {                // issue next loads BEFORE barrier (WAR on regs)
      a0 = *(const bf16x8*)(Ag + (kt + 1) * 32);
      a1 = *(const bf16x8*)(Ag + (kt + 1) * 32 + 8);
      b0 = *(const bf16x8*)(Bg + (kt + 1) * 32);
      b1 = *(const bf16x8*)(Bg + (kt + 1) * 32 + 8);
    }
    __syncthreads();
    bf16x8 af[4], bfv[4];
#pragma unroll
    for (int mi = 0; mi < 4; ++mi) af[mi] = *(const bf16x8*)&As[db][wr * 64 + mi * 16 + fr][kq];
#pragma unroll
    for (int ni = 0; ni < 4; ++ni) bfv[ni] = *(const bf16x8*)&Bs[db][wc * 64 + ni * 16 + fr][kq];
#pragma unroll
    for (int mi = 0; mi < 4; ++mi)
#pragma unroll
      for (int ni = 0; ni < 4; ++ni)
        acc[mi][ni] = mfma16(af[mi], bfv[ni], acc[mi][ni]);
  }
#pragma unroll
  for (int mi = 0; mi < 4; ++mi)
#pragma unroll
    for (int ni = 0; ni < 4; ++ni)
#pragma unroll
      for (int j = 0; j < 4; ++j) {
        int gm = tm + wr * 64 + mi * 16 + (l >> 4) * 4 + j;
        int gn = tn + wc * 64 + ni * 16 + fr;
        float v = acc[mi][ni][j] + bias[gn];
        int b = gm >> 10, s = gm & 1023;
        unsigned gnu = (unsigned)gn;
        unsigned h = gnu / 192u;
        unsigned rem = gnu - h * 192u;
        unsigned which = rem >> 6, d = rem & 63u;
        int bh = b * 16 + (int)h;
        u16 bv = f2bu(v);
        if (which == 0u)      qb[((size_t)bh * 1024 + s) * 64 + d] = bv;
        else if (which == 1u) kb[((size_t)bh * 1024 + s) * 64 + d] = bv;
        else                  vt[((size_t)bh * 64 + d) * 1024 + s] = bv;
      }
}

// ---------------- attention: swapped-QK register-P; block = (bh, 64 q-rows), 4 waves
// K/V LDS-staged+shared; merged qrel/band buffer (in-place overwrite) -> 4 blocks/CU
#define QRS 132    // merged qrel/band row stride u16 (264B -> conflict-free b128 reads)
__global__ __launch_bounds__(256) void attn_k(
    const u16* __restrict__ qb, const u16* __restrict__ kb,
    const u16* __restrict__ vt, const u16* __restrict__ tb,
    const u16* __restrict__ tbT, const unsigned long long* __restrict__ bm64,
    u16* __restrict__ vals) {
  __shared__ u16 Kbuf[64 * 64];        // 8 KB: K chunk [64 k][64 d], slot^=(k&7)
  __shared__ u16 Vbuf[64 * 64];        // 8 KB: V^T chunk [64 d][64 k-permuted], slot^=(d&7)
  __shared__ u16 qrs[64 * QRS];        // 16.9 KB: qrel[q][r] -> overwritten by band P in place
  const int tid = threadIdx.x;
  const int l = tid & 63, w = tid >> 6;
  const int fr = l & 15, g = l >> 4, kq = g * 8, g4 = g * 4;
  const int blk = ((int)blockIdx.x & 7) * 128 + ((int)blockIdx.x >> 3);  // XCD swizzle
  const int qt = blk & 15, bh = blk >> 4;
  const int b = bh >> 4, h = bh & 15;
  const int qbase = qt * 64 + w * 16;            // this wave's q-row base
  const int q = qbase + fr;                      // this LANE's q-row (swapped layout)
  const u16* kbase = kb + (size_t)bh * 65536;
  const u16* vbase = vt + (size_t)bh * 65536;
  // staging regs + loaders (cooperative across all 256 threads)
  const int srow0 = tid >> 3, sslot = tid & 7;
  const int p5 = (sslot >> 2) & 1, p4 = (sslot >> 1) & 1, p3 = sslot & 1;
  const int vb0 = p5 * 32 + p3 * 16 + p4 * 4;    // V permuted-store base (u16 units)
  bf16x8 sK0, sK1, sV0, sV1;
  auto ldStage = [&](int c) {
    const u16* ks = kbase + (size_t)(c * 64) * 64;
    sK0 = *(const bf16x8*)(ks + srow0 * 64 + sslot * 8);
    sK1 = *(const bf16x8*)(ks + (srow0 + 32) * 64 + sslot * 8);
    const u16* vs = vbase + c * 64 + sslot * 8;
    sV0 = *(const bf16x8*)(vs + (size_t)srow0 * 1024);
    sV1 = *(const bf16x8*)(vs + (size_t)(srow0 + 32) * 1024);
  };
  auto wrV = [&](int d, bf16x8 v) {
    int s0 = vb0 >> 3, sub = vb0 & 7;
    int a0 = d * 64 + ((s0 ^ (d & 7)) * 8 + sub);
    int a1 = d * 64 + (((s0 + 1) ^ (d & 7)) * 8 + sub);
    u16x4 lo = {v[0], v[1], v[2], v[3]};
    u16x4 hi = {v[4], v[5], v[6], v[7]};
    *(u16x4*)&Vbuf[a0] = lo;
    *(u16x4*)&Vbuf[a1] = hi;
  };
  auto wrStage = [&]() {
    *(bf16x8*)&Kbuf[srow0 * 64 + (sslot ^ (srow0 & 7)) * 8] = sK0;
    *(bf16x8*)&Kbuf[(srow0 + 32) * 64 + (sslot ^ ((srow0 + 32) & 7)) * 8] = sK1;
    wrV(srow0, sV0);
    wrV(srow0 + 32, sV1);
  };
  ldStage(0);                                    // issue chunk-0 loads early
  // Q fragments (lane fr holds q-row qbase+fr)
  const u16* qrow = qb + ((size_t)bh * 1024 + qbase) * 64;
  bf16x8 qa0 = *(const bf16x8*)(qrow + fr * 64 + kq);
  bf16x8 qa1 = *(const bf16x8*)(qrow + fr * 64 + 32 + kq);
  // pass 0 (swapped): qrel[q=fr][r = t*16+g4+j]
  f32x4 a_t0 = {}, a_t8 = {};
#pragma unroll
  for (int t = 0; t < 9; ++t) {
    const u16* tp = tb + (t * 16 + fr) * 64 + kq;
    bf16x8 t0 = *(const bf16x8*)(tp);
    bf16x8 t1 = *(const bf16x8*)(tp + 32);
    f32x4 a = {0.f, 0.f, 0.f, 0.f};
    a = mfma16(t0, qa0, a);
    a = mfma16(t1, qa1, a);
#pragma unroll
    for (int j = 0; j < 4; ++j) {
      int rg = t * 16 + g4 + j;
      if (rg < 129) qrs[(w * 16 + fr) * QRS + rg] = f2bu(a[j]);
    }
    if (t == 0) a_t0 = a;
    if (t == 8) a_t8 = a;
  }
  const float q0r = __shfl(a_t0[0], fr);     // qrel[q=fr][0]
  const float q128r = __shfl(a_t8[0], fr);   // qrel[q=fr][128]
  u16* qpl = qrs + (w * 16 + fr) * QRS;      // this lane's merged qrel/band row
  // targeted zeroing: band slots whose k is out-of-range or clip_pad-edge are never
  // written by pass-1 (and their qrel value is never read) -> must read as 0 in band MFMA
  if (g == 0) {
    int loEnd = (q == 0) ? 63 : (q <= 63 ? 64 - q : 0);
    for (int r = 1; r <= loEnd; ++r) qpl[r] = 0;
    int hiStart = (q >= 960 && q <= 1022) ? (1087 - q) : (q == 1023 ? 65 : 128);
    for (int r = hiStart; r <= 127; ++r) qpl[r] = 0;
  }
  // mask: one u64 per (q, chunk); prefetch next chunk's words
  const unsigned* bmp = (const unsigned*)(bm64 + (((size_t)b << 10) + q) * 16);
  unsigned bmLoX = bmp[0], bmHiX = bmp[1], bmLoY = 0, bmHiY = 0;
  const float C1 = 0.18033688011112042f;   // 0.125*log2(e)
  const float C2 = 17.31234049066756f;     // 12*log2(e)
  float ps = 0.f, psA = 0.f, psB = 0.f;
  f32x4 acc[4] = {};
  auto kfrag = [&](int t2, int hh) -> bf16x8 {
    int rk = t2 * 16 + fr;
    int sl = (g + 4 * hh) ^ (rk & 7);
    return *(const bf16x8*)&Kbuf[rk * 64 + sl * 8];
  };
  auto vfrag = [&](int dg, int hh) -> bf16x8 {
    int d = dg * 16 + fr;
    int sl = (hh * 4 + g) ^ (d & 7);
    return *(const bf16x8*)&Vbuf[d * 64 + sl * 8];
  };
#pragma unroll 1
  for (int c = 0; c < 16; ++c) {
    __syncthreads();                     // all waves done reading prev chunk bufs
    wrStage();                           // write staged chunk c (waits its vmcnt)
    if (c < 15) {
      ldStage(c + 1);                    // issue next loads BEFORE barrier (WAR on regs)
      bmLoY = bmp[(c + 1) * 2];
      bmHiY = bmp[(c + 1) * 2 + 1];
    }
    __syncthreads();                     // bufs ready
    __builtin_amdgcn_s_setprio(1);
    bf16x8 pa0, pa1;                     // P fragments (built in registers)
#pragma unroll
    for (int t2 = 0; t2 < 4; ++t2) {
      f32x4 a = {0.f, 0.f, 0.f, 0.f};
      a = mfma16(kfrag(t2, 0), qa0, a);  // swapped: lane holds S[k=g4+j][q=fr]
      a = mfma16(kfrag(t2, 1), qa1, a);
      int ncol = c * 64 + t2 * 16;
      unsigned wsel = (t2 < 2) ? bmLoX : bmHiX;
      if (ncol + 79 <= qbase) {          // whole tile: rdx = 0
#pragma unroll
        for (int j = 0; j < 4; ++j) {
          float s = a[j] + q0r;
          unsigned bit = (wsel >> (g4 + ((t2 & 1) * 16 + j))) & 1u;
          float arg = bit ? __builtin_fmaf(s, C1, -C2) : -1e30f;
          float e = __builtin_amdgcn_exp2f(arg);
          ps += e; psA += e;
          u16 pv = f2bu_fast(e);
          if (t2 < 2) pa0[t2 * 4 + j] = (short)pv; else pa1[(t2 - 2) * 4 + j] = (short)pv;
        }
      } else if (ncol >= qbase + 79) {   // whole tile: rdx = 128
#pragma unroll
        for (int j = 0; j < 4; ++j) {
          float s = a[j] + q128r;
          unsigned bit = (wsel >> (g4 + ((t2 & 1) * 16 + j))) & 1u;
          float arg = bit ? __builtin_fmaf(s, C1, -C2) : -1e30f;
          float e = __builtin_amdgcn_exp2f(arg);
          ps += e; psB += e;
          u16 pv = f2bu_fast(e);
          if (t2 < 2) pa0[t2 * 4 + j] = (short)pv; else pa1[(t2 - 2) * 4 + j] = (short)pv;
        }
      } else {                            // mixed tile: read qrel slot, overwrite with P
#pragma unroll
        for (int j = 0; j < 4; ++j) {
          int kgl = ncol + g4 + j;
          int dd = kgl - q;
          int rdx = dd < -64 ? 0 : (dd > 64 ? 128 : dd + 64);
          bool ov = (q >= 1 && q <= 1022);
          bool edge = ov && (kgl == 0 || kgl == 1023);
          if (edge) rdx = (kgl == 0) ? 0 : 128;
          float s = a[j] + b2f(qpl[rdx]);
          unsigned bit = (wsel >> (g4 + ((t2 & 1) * 16 + j))) & 1u;
          float arg = bit ? __builtin_fmaf(s, C1, -C2) : -1e30f;
          float e = __builtin_amdgcn_exp2f(arg);
          ps += e;
          psA += (rdx == 0) ? e : 0.f;
          psB += (rdx == 128) ? e : 0.f;
          u16 pv = f2bu_fast(e);
          if (t2 < 2) pa0[t2 * 4 + j] = (short)pv; else pa1[(t2 - 2) * 4 + j] = (short)pv;
          int r = dd + 64;
          if (r >= 1 && r <= 127 && !edge) qpl[r] = pv;   // in-place band store
        }
      }
    }
    // PV: P-in-registers (k-permuted) x V (stored in matching k-order)
#pragma unroll
    for (int dg = 0; dg < 4; ++dg) {
      acc[dg] = mfma16(pa0, vfrag(dg, 0), acc[dg]);
      acc[dg] = mfma16(pa1, vfrag(dg, 1), acc[dg]);
    }
    __builtin_amdgcn_s_setprio(0);
    bmLoX = bmLoY; bmHiX = bmHiY;
  }
  // slot 0 held qrel[0] for pass-1; band MFMA needs 0 there (r=0 via rank-1 term)
  if (g == 0) qpl[0] = 0;
  // reduce row sums across the 4 groups (each lane then holds totals for q=fr)
#pragma unroll
  for (int off = 16; off <= 32; off <<= 1) {
    ps += __shfl_xor(ps, off);
    psA += __shfl_xor(psA, off);
    psB += __shfl_xor(psB, off);
  }
  // redistribute to output layout (elem j -> q-row g4+j)
  float psO[4], psAO[4], psBO[4];
#pragma unroll
  for (int j = 0; j < 4; ++j) {
    psO[j] = __shfl(ps, g4 + j);
    psAO[j] = __shfl(psA, g4 + j);
    psBO[j] = __shfl(psB, g4 + j);
  }
  // band MFMAs + rank-1 r=0/128 + normalize + store
  const u16* srow = qrs + (w * 16 + fr) * QRS + kq;
  bf16x8 sa0 = *(const bf16x8*)(srow);
  bf16x8 sa1 = *(const bf16x8*)(srow + 32);
  bf16x8 sa2 = *(const bf16x8*)(srow + 64);
  bf16x8 sa3 = *(const bf16x8*)(srow + 96);
#pragma unroll
  for (int dg = 0; dg < 4; ++dg) {
    int dc = dg * 16 + fr;
    const u16* tq = tbT + dc * 160 + kq;
    f32x4 av = acc[dg];
    av = mfma16(sa0, *(const bf16x8*)(tq), av);
    av = mfma16(sa1, *(const bf16x8*)(tq + 32), av);
    av = mfma16(sa2, *(const bf16x8*)(tq + 64), av);
    av = mfma16(sa3, *(const bf16x8*)(tq + 96), av);
    float t0v = b2f(tb[dc]);
    float t128v = b2f(tb[128 * 64 + dc]);
#pragma unroll
    for (int j = 0; j < 4; ++j) {
      float val = (av[j] + psAO[j] * t0v + psBO[j] * t128v) / psO[j];
      int sg = qbase + g4 + j;
      vals[((size_t)b * 1024 + sg) * 1024 + h * 64 + dc] = f2bu(val);
    }
  }
}

// ---------------- output GEMM (bf16 in, dbuf LDS, 1 barrier/K-step, loads pre-barrier)
__global__ __launch_bounds__(256) void gemm_out_k(
    const u16* __restrict__ A, const u16* __restrict__ Bw,
    const float* __restrict__ bias, float* __restrict__ out) {
  __shared__ u16 As[2][128][40];
  __shared__ u16 Bs[2][128][40];
  const int tid = threadIdx.x;
  const int l = tid & 63, w = tid >> 6;
  const int wr = w >> 1, wc = w & 1;
  const int fr = l & 15, kq = (l >> 4) * 8;
  const int bid = blockIdx.x;
  const int tn = (bid % 8) * 128, tm = (bid / 8) * 128;
  const int sr = tid >> 1, sc = (tid & 1) * 16;
  const u16* Ag = A + (size_t)(tm + sr) * 1024 + sc;
  const u16* Bg = Bw + (size_t)(tn + sr) * 1024 + sc;
  f32x4 acc[4][4] = {};
  bf16x8 a0, a1, b0, b1;
  a0 = *(const bf16x8*)(Ag);      a1 = *(const bf16x8*)(Ag + 8);
  b0 = *(const bf16x8*)(Bg);      b1 = *(const bf16x8*)(Bg + 8);
#pragma unroll 1
  for (int kt = 0; kt < 32; ++kt) {
    const int db = kt & 1;
    *(bf16x8*)&As[db][sr][sc] = a0; *(bf16x8*)&As[db][sr][sc + 8] = a1;
    *(bf16x8*)&Bs[db][sr][sc] = b0; *(bf16x8*)&Bs[db][sr][sc + 8] = b1;
    if (kt < 31) {                // issue next loads BEFORE barrier (WAR on regs)
      a0 = *(const bf16x8*)(Ag + (kt + 1) * 32);
      a1 = *(const bf16x8*)(Ag + (kt + 1) * 32 + 8);
      b0 = *(const bf16x8*)(Bg + (kt + 1) * 32);
      b1 = *(const bf16x8*)(Bg + (kt + 1) * 32 + 8);
    }
    __syncthreads();
    bf16x8 af[4], bfv[4];
#pragma unroll
    for (int mi = 0; mi < 4; ++mi) af[mi] = *(const bf16x8*)&As[db][wr * 64 + mi * 16 + fr][kq];
#pragma unroll
    for (int ni = 0; ni < 4; ++ni) bfv[ni] = *(const bf16x8*)&Bs[db][wc * 64 + ni * 16 + fr][kq];
#pragma unroll
    for (int mi = 0; mi < 4; ++mi)
#pragma unroll
      for (int ni = 0; ni < 4; ++ni)
        acc[mi][ni] = mfma16(af[mi], bfv[ni], acc[mi][ni]);
  }
#pragma unroll
  for (int mi = 0; mi < 4; ++mi)
#pragma unroll
    for (int ni = 0; ni < 4; ++ni)
#pragma unroll
      for (int j = 0; j < 4; ++j) {
        int gm = tm + wr * 64 + mi * 16 + (l >> 4) * 4 + j;
        int gn = tn + wc * 64 + ni * 16 + fr;
        out[(size_t)gm * 1024 + gn] = acc[mi][ni][j] + bias[gn];
      }
}

extern "C" void kernel_launch(void* const* d_in, const int* in_sizes, int n_in,
                              void* d_out, int out_size, void* d_ws, size_t ws_size,
                              hipStream_t stream) {
  (void)in_sizes; (void)n_in; (void)out_size; (void)ws_size;
  const float* x    = (const float*)d_in[0];
  const float* qkvw = (const float*)d_in[1];
  const float* qkvb = (const float*)d_in[2];
  const float* ow   = (const float*)d_in[3];
  const float* ob   = (const float*)d_in[4];
  const float* tbl  = (const float*)d_in[5];
  const int*   mask = (const int*)d_in[6];
  float* out = (float*)d_out;
  char* ws = (char*)d_ws;
  u16* tb   = (u16*)(ws);
  u16* tbT  = (u16*)(ws + 20480);
  u16* qb   = (u16*)(ws + 40960);
  u16* kb   = (u16*)(ws + 40960 + 8388608ull);
  u16* vt   = (u16*)(ws + 40960 + 2ull * 8388608ull);
  u16* xbvals = (u16*)(ws + 40960 + 3ull * 8388608ull);   // xb (pre-attn) / vals (post)
  unsigned long long* bm64 = (unsigned long long*)(ws + 40960 + 4ull * 8388608ull);
  u16* wb   = (u16*)(ws + 40960 + 4ull * 8388608ull + 524288ull);
  u16* owb  = (u16*)(ws + 40960 + 4ull * 8388608ull + 524288ull + 6291456ull);

  prep_all_k<<<dim3(20520), dim3(256), 0, stream>>>(mask, bm64, x, qkvw, ow,
                                                    xbvals, wb, owb, tbl, tb, tbT);
  gemm_qkv_k<<<dim3(768), dim3(256), 0, stream>>>(xbvals, wb, qkvb, qb, kb, vt);
  attn_k<<<dim3(1024), dim3(256), 0, stream>>>(qb, kb, vt, tb, tbT, bm64, xbvals);
  gemm_out_k<<<dim3(256), dim3(256), 0, stream>>>(xbvals, owb, ob, out);
}